// Round 12
// baseline (585.747 us; speedup 1.0000x reference)
//
#include <hip/hip_runtime.h>
#include <hip/hip_bf16.h>

// AttributeGNN, bf16 MFMA, fp32 accumulate. B=16384, A=16, D=256.
// R12: L2 working-set fix. The 4.25MB weight set sits just over the 4MiB
// per-XCD L2 and is continuously evicted by the edge/attr streams (~475MB
// HBM refetch = the FETCH excess seen since R5). Fix: run the a-loop as TWO
// sequential half-dispatches (a in [0,8) then [8,16)) -> 2.4MB weight set per
// dispatch, L2-resident on every XCD. indiv: half 0 stores, half 1 load+add.
// Also: depth-4 B-fragment register pipeline in gemm32g.

typedef __bf16 bf16_t;
typedef __bf16 bf16x4 __attribute__((ext_vector_type(4)));
typedef __bf16 bf16x8 __attribute__((ext_vector_type(8)));
typedef float f32x4 __attribute__((ext_vector_type(4)));

#define NB 16384
#define NA 16
#define ND 256

// XOR swizzle for bf16 LDS tiles [32][256]: slot = chunk ^ (row&15) is a full
// permutation over the 32 8-elem chunks -> 2 lanes/bank (free) on A-reads.
__device__ __forceinline__ int swz(int r, int c) {
    return r * 256 + (c ^ ((r & 15) << 3));
}

__device__ __forceinline__ bf16x8 cvt8(f32x4 a, f32x4 b) {
    bf16x8 r;
    r[0] = (bf16_t)a.x; r[1] = (bf16_t)a.y; r[2] = (bf16_t)a.z; r[3] = (bf16_t)a.w;
    r[4] = (bf16_t)b.x; r[5] = (bf16_t)b.y; r[6] = (bf16_t)b.z; r[7] = (bf16_t)b.w;
    return r;
}

// 32(M) x 256(K) x 32(N-slice) GEMM. A from swizzled LDS; B from global in
// fragment layout (1KB coalesced, L2-resident), depth-4 register pipeline.
// C/D layout per m89: col = lane&15, row = (lane>>4)*4 + j.
__device__ __forceinline__ void gemm32g(const bf16_t* a_lds, const bf16_t* __restrict__ Bf,
                                        f32x4 acc[2][2], int lane, int wc)
{
    const int lr = lane & 15, lhi = lane >> 4;
    const bf16_t* bp = Bf + (size_t)wc * 16 * 512 + lane * 8;
    bf16x8 bq0[4], bq1[4];
#pragma unroll
    for (int p = 0; p < 4; ++p) {
        bq0[p] = *(const bf16x8*)&bp[p * 512];
        bq1[p] = *(const bf16x8*)&bp[(8 + p) * 512];
    }
#pragma unroll
    for (int ks = 0; ks < 8; ++ks) {
        const int kc = ks * 32 + lhi * 8;
        bf16x8 af0 = *(const bf16x8*)&a_lds[swz(lr, kc)];
        bf16x8 af1 = *(const bf16x8*)&a_lds[swz(16 + lr, kc)];
        acc[0][0] = __builtin_amdgcn_mfma_f32_16x16x32_bf16(af0, bq0[ks & 3], acc[0][0], 0, 0, 0);
        acc[1][0] = __builtin_amdgcn_mfma_f32_16x16x32_bf16(af1, bq0[ks & 3], acc[1][0], 0, 0, 0);
        acc[0][1] = __builtin_amdgcn_mfma_f32_16x16x32_bf16(af0, bq1[ks & 3], acc[0][1], 0, 0, 0);
        acc[1][1] = __builtin_amdgcn_mfma_f32_16x16x32_bf16(af1, bq1[ks & 3], acc[1][1], 0, 0, 0);
        if (ks + 4 < 8) {
            bq0[ks & 3] = *(const bf16x8*)&bp[(ks + 4) * 512];
            bq1[ks & 3] = *(const bf16x8*)&bp[(8 + ks + 4) * 512];
        }
    }
}

// ---- W_agg [256][512] fp32 -> W1f / W2f fragment layout (bf16).
__global__ void prep_wfrag(const float* __restrict__ W,
                           bf16_t* __restrict__ W1f, bf16_t* __restrict__ W2f)
{
    int t = blockIdx.x * 256 + threadIdx.x;
    int lane = t & 63;
    int ks = (t >> 6) & 7;
    int nt = (t >> 9) & 15;
    int half = t >> 13;
    int row = nt * 16 + (lane & 15);
    int col = ks * 32 + (lane >> 4) * 8;
    const float* src = W + (size_t)row * 512 + half * 256 + col;
    bf16_t* dst = (half ? W2f : W1f) + ((nt * 8 + ks) * 64 + lane) * 8;
    bf16x8 v;
#pragma unroll
    for (int m = 0; m < 8; ++m) v[m] = (bf16_t)src[m];
    *(bf16x8*)dst = v;
}

// ---- P[a][i][j] fp32 -> Pt[a][j][i] bf16 via LDS transpose.
__global__ void transpose_P(const float* __restrict__ Pf, const float* __restrict__ Pb,
                            bf16_t* __restrict__ Pft, bf16_t* __restrict__ Pbt)
{
    __shared__ float t[32][33];
    int blk = blockIdx.x;
    int mat = blk >> 10;
    int rest = blk & 1023;
    int a = rest >> 6;
    int tile = rest & 63;
    int i0 = (tile >> 3) * 32;
    int j0 = (tile & 7) * 32;
    const float* src = (mat ? Pb : Pf) + a * 65536;
    bf16_t* dst = (mat ? Pbt : Pft) + a * 65536;
    int r = threadIdx.x >> 5, c = threadIdx.x & 31;
#pragma unroll
    for (int it = 0; it < 4; ++it)
        t[r + 8 * it][c] = src[(i0 + r + 8 * it) * 256 + j0 + c];
    __syncthreads();
#pragma unroll
    for (int it = 0; it < 4; ++it)
        dst[(j0 + r + 8 * it) * 256 + i0 + c] = (bf16_t)t[c][r + 8 * it];
}

// ---- row-major bf16 [16][256][256] -> fragment layout.
__global__ void prep_pfrag(const bf16_t* __restrict__ Pt, bf16_t* __restrict__ Pfr)
{
    int t = blockIdx.x * 256 + threadIdx.x;
    int lane = t & 63;
    int ks = (t >> 6) & 7;
    int nt = (t >> 9) & 15;
    int a = t >> 13;
    bf16x8 v = *(const bf16x8*)&Pt[(size_t)a * 65536 + (nt * 16 + (lane & 15)) * 256 + ks * 32 + (lane >> 4) * 8];
    *(bf16x8*)&Pfr[(size_t)a * 65536 + ((nt * 8 + ks) * 64 + lane) * 8] = v;
}

// ---- edge [b][a][d] fp32 -> edgeT [a][b][d] bf16 (linear reads).
__global__ void edge_tr(const float* __restrict__ edge, bf16_t* __restrict__ edgeT)
{
    size_t t = (size_t)blockIdx.x * 256 + threadIdx.x;
    size_t b = t >> 9;
    int a = (int)((t >> 5) & 15);
    int d8 = (int)(t & 31);
    const float* src = edge + (b << 12) + (a << 8) + (d8 << 3);
    f32x4 v0 = *(const f32x4*)src;
    f32x4 v1 = *(const f32x4*)(src + 4);
    *(bf16x8*)&edgeT[(((size_t)a << 14) + b) * 256 + (d8 << 3)] = cvt8(v0, v1);
}

// ---- fused main over a in [a0, a0+8). LDS 64KB, 2 blocks/CU.
__global__ __launch_bounds__(512, 4)
void fused_main(const float* __restrict__ img, const float* __restrict__ bias,
                const bf16_t* __restrict__ edgeT,
                const bf16_t* __restrict__ W1f, const bf16_t* __restrict__ W2f,
                const bf16_t* __restrict__ Pff, const bf16_t* __restrict__ Pbf,
                const float* __restrict__ sw, float* __restrict__ out,
                int a0, int accum)
{
    __shared__ bf16_t E[2][32 * 256];   // 2 x 16 KB edge dbuf
    __shared__ bf16_t G[32 * 256];      // 16 KB agg
    __shared__ bf16_t R[32 * 256];      // 16 KB attr bf16

    const int tid = threadIdx.x;
    const int lane = tid & 63;
    const int wc = tid >> 6;            // 0..7: 32-col slice
    const int lr = lane & 15;
    const int lhi = lane >> 4;
    const int brow0 = blockIdx.x * 32;
    const int sr = tid >> 4;            // staging row 0..31
    const int c16 = (tid & 15) * 16;    // staging col base

    // ---- prologue: img -> E[0] (bf16 swz)
    {
        const float* ip = img + (size_t)(brow0 + sr) * ND + c16;
        f32x4 v0 = *(const f32x4*)(ip + 0), v1 = *(const f32x4*)(ip + 4);
        f32x4 v2 = *(const f32x4*)(ip + 8), v3 = *(const f32x4*)(ip + 12);
        *(bf16x8*)&E[0][swz(sr, c16)] = cvt8(v0, v1);
        *(bf16x8*)&E[0][swz(sr, c16 + 8)] = cvt8(v2, v3);
    }
    __syncthreads();

    // ---- T = img @ W1^T + bias (kept in 16 regs; W1 via L2 fragment path)
    f32x4 T[2][2];
#pragma unroll
    for (int ni = 0; ni < 2; ++ni) {
        float bz = bias[wc * 32 + ni * 16 + lr];
        T[0][ni] = (f32x4){bz, bz, bz, bz};
        T[1][ni] = (f32x4){bz, bz, bz, bz};
    }
    gemm32g(&E[0][0], W1f, T, lane, wc);
    __syncthreads();                    // E[0] free

    // ---- edge(a0) -> E[0] (plain loads: edgeT is L3-resident)
    {
        const bf16_t* ep = edgeT + ((size_t)a0 * NB + brow0 + sr) * ND + c16;
        *(bf16x8*)&E[0][swz(sr, c16)] = *(const bf16x8*)ep;
        *(bf16x8*)&E[0][swz(sr, c16 + 8)] = *(const bf16x8*)(ep + 8);
    }
    __syncthreads();

    f32x4 indiv[2][2];
#pragma unroll
    for (int mi = 0; mi < 2; ++mi)
#pragma unroll
        for (int ni = 0; ni < 2; ++ni)
            indiv[mi][ni] = (f32x4){0.f, 0.f, 0.f, 0.f};

    for (int ai = 0; ai < 8; ++ai) {
        const int a = a0 + ai;
        const int cur = ai & 1;
        const bool pf = (ai + 1 < 8);
        f32x4 acc[2][2];

        // ---- phase 1: issue edge(a+1) loads; GEMM1 = T + edge @ W2^T (L2 frags)
        bf16x8 elo, ehi;
        if (pf) {
            const bf16_t* ep = edgeT + ((size_t)(a + 1) * NB + brow0 + sr) * ND + c16;
            elo = *(const bf16x8*)ep;
            ehi = *(const bf16x8*)(ep + 8);
        }
#pragma unroll
        for (int mi = 0; mi < 2; ++mi)
#pragma unroll
            for (int ni = 0; ni < 2; ++ni)
                acc[mi][ni] = T[mi][ni];
        gemm32g(&E[cur][0], W2f, acc, lane, wc);
#pragma unroll
        for (int mi = 0; mi < 2; ++mi)
#pragma unroll
            for (int ni = 0; ni < 2; ++ni)
#pragma unroll
                for (int j = 0; j < 4; ++j)
                    G[swz(mi * 16 + lhi * 4 + j, wc * 32 + ni * 16 + lr)] = (bf16_t)acc[mi][ni][j];
        if (pf) {   // commit edge(a+1); latency hidden under GEMM1
            *(bf16x8*)&E[cur ^ 1][swz(sr, c16)] = elo;
            *(bf16x8*)&E[cur ^ 1][swz(sr, c16 + 8)] = ehi;
        }
        __syncthreads();

        // ---- phase 2: attr = agg @ Pf[a] -> R (bf16 swz)
#pragma unroll
        for (int mi = 0; mi < 2; ++mi)
#pragma unroll
            for (int ni = 0; ni < 2; ++ni)
                acc[mi][ni] = (f32x4){0.f, 0.f, 0.f, 0.f};
        gemm32g(&G[0], Pff + (size_t)a * 65536, acc, lane, wc);
#pragma unroll
        for (int mi = 0; mi < 2; ++mi)
#pragma unroll
            for (int ni = 0; ni < 2; ++ni)
#pragma unroll
                for (int j = 0; j < 4; ++j)
                    R[swz(mi * 16 + lhi * 4 + j, wc * 32 + ni * 16 + lr)] = (bf16_t)acc[mi][ni][j];
        __syncthreads();

        // ---- phase 3: attr readback -> full-line nt fp32 stores;
        //      GEMM3: proj = relu(attr @ Pb[a]); indiv += proj * sw[a]
        {
            float* op = out + (size_t)brow0 * (NA * ND) + (size_t)a * ND;
#pragma unroll
            for (int h = 0; h < 2; ++h) {
                int r = (tid >> 5) + h * 16;
                int ce = (tid & 31) * 8;
                bf16x8 v = *(const bf16x8*)&R[swz(r, ce)];
                f32x4 lo = {(float)v[0], (float)v[1], (float)v[2], (float)v[3]};
                f32x4 hi = {(float)v[4], (float)v[5], (float)v[6], (float)v[7]};
                float* p = op + (size_t)r * (NA * ND) + ce;
                __builtin_nontemporal_store(lo, (f32x4*)p);
                __builtin_nontemporal_store(hi, (f32x4*)(p + 4));
            }
        }
#pragma unroll
        for (int mi = 0; mi < 2; ++mi)
#pragma unroll
            for (int ni = 0; ni < 2; ++ni)
                acc[mi][ni] = (f32x4){0.f, 0.f, 0.f, 0.f};
        gemm32g(&R[0], Pbf + (size_t)a * 65536, acc, lane, wc);
        const float swa = sw[a];
#pragma unroll
        for (int mi = 0; mi < 2; ++mi)
#pragma unroll
            for (int ni = 0; ni < 2; ++ni)
#pragma unroll
                for (int j = 0; j < 4; ++j)
                    indiv[mi][ni][j] += fmaxf(acc[mi][ni][j], 0.f) * swa;
        __syncthreads();
    }

    // ---- individual_embeddings: half 0 stores, half 1 accumulates (sequential
    // dispatches on one stream -> dispatch 0's writes visible to dispatch 1).
#pragma unroll
    for (int mi = 0; mi < 2; ++mi)
#pragma unroll
        for (int ni = 0; ni < 2; ++ni)
#pragma unroll
            for (int j = 0; j < 4; ++j) {
                int r = mi * 16 + lhi * 4 + j;
                int c = wc * 32 + ni * 16 + lr;
                float* p = &out[(size_t)NB * NA * ND + (size_t)(brow0 + r) * ND + c];
                float v = indiv[mi][ni][j];
                if (accum) v += *p;
                *p = v;
            }
}

extern "C" void kernel_launch(void* const* d_in, const int* in_sizes, int n_in,
                              void* d_out, int out_size, void* d_ws, size_t ws_size,
                              hipStream_t stream)
{
    const float* img  = (const float*)d_in[0];
    const float* edge = (const float*)d_in[1];
    const float* Wagg = (const float*)d_in[2];
    const float* bagg = (const float*)d_in[3];
    const float* Pf   = (const float*)d_in[4];
    const float* Pb   = (const float*)d_in[5];
    const float* sw   = (const float*)d_in[6];
    float* out = (float*)d_out;

    char* ws = (char*)d_ws;
    bf16_t* W1f = (bf16_t*)(ws);                   // 128 KB fragment layout
    bf16_t* W2f = (bf16_t*)(ws + 131072);          // 128 KB
    bf16_t* Pff = (bf16_t*)(ws + 262144);          // 2 MB
    bf16_t* Pbf = (bf16_t*)(ws + 2359296);         // 2 MB
    bf16_t* edT = (bf16_t*)(ws + 4456448);         // 134.2 MB [a][b][d] bf16
    // temps alias edT (dead before edge_tr runs; stream-ordered)
    bf16_t* Ptf = (bf16_t*)(ws + 4456448);         // 2 MB row-major temp
    bf16_t* Ptb = (bf16_t*)(ws + 6553600);         // 2 MB row-major temp

    prep_wfrag<<<64, 256, 0, stream>>>(Wagg, W1f, W2f);
    transpose_P<<<2048, 256, 0, stream>>>(Pf, Pb, Ptf, Ptb);
    prep_pfrag<<<512, 256, 0, stream>>>(Ptf, Pff);
    prep_pfrag<<<512, 256, 0, stream>>>(Ptb, Pbf);
    edge_tr<<<32768, 256, 0, stream>>>(edge, edT);
    fused_main<<<NB / 32, 512, 0, stream>>>(img, bagg, edT, W1f, W2f, Pff, Pbf, sw, out, 0, 0);
    fused_main<<<NB / 32, 512, 0, stream>>>(img, bagg, edT, W1f, W2f, Pff, Pbf, sw, out, 8, 1);
}

// Round 13
// 551.190 us; speedup vs baseline: 1.0627x; 1.0627x over previous
//
#include <hip/hip_runtime.h>
#include <hip/hip_bf16.h>

// AttributeGNN, bf16 MFMA, fp32 accumulate. B=16384, A=16, D=256.
// R13: barrier-drain fix (T3/T4 minimum). __syncthreads() forces
// s_waitcnt vmcnt(0) before s_barrier -> every phase drains its global
// stores/loads (nt stores ack at memory!). Replace with raw s_barrier +
// lgkmcnt(0)-only waits; delete the redundant phase-3 barrier; attr stores
// plain (L2-commit retire) and issued after phase-3 GEMM. Single dispatch.

typedef __bf16 bf16_t;
typedef __bf16 bf16x4 __attribute__((ext_vector_type(4)));
typedef __bf16 bf16x8 __attribute__((ext_vector_type(8)));
typedef float f32x4 __attribute__((ext_vector_type(4)));

#define NB 16384
#define NA 16
#define ND 256

// LDS-ordering barrier WITHOUT the vmcnt(0) drain __syncthreads() emits:
// this wave's LDS ops complete (lgkmcnt(0)), then raw s_barrier. Global
// loads/stores stay in flight across it (counted waits at their consumers).
#define PHASE_BAR() do {                                    \
    asm volatile("s_waitcnt lgkmcnt(0)" ::: "memory");      \
    __builtin_amdgcn_sched_barrier(0);                      \
    __builtin_amdgcn_s_barrier();                           \
} while (0)

// XOR swizzle for bf16 LDS tiles [32][256]: slot = chunk ^ (row&15) is a full
// permutation over the 32 8-elem chunks -> 2 lanes/bank (free) on A-reads.
__device__ __forceinline__ int swz(int r, int c) {
    return r * 256 + (c ^ ((r & 15) << 3));
}

__device__ __forceinline__ bf16x8 cvt8(f32x4 a, f32x4 b) {
    bf16x8 r;
    r[0] = (bf16_t)a.x; r[1] = (bf16_t)a.y; r[2] = (bf16_t)a.z; r[3] = (bf16_t)a.w;
    r[4] = (bf16_t)b.x; r[5] = (bf16_t)b.y; r[6] = (bf16_t)b.z; r[7] = (bf16_t)b.w;
    return r;
}

// 32(M) x 256(K) x 32(N-slice) GEMM. A from swizzled LDS; B from global in
// fragment layout (1KB coalesced, L2-resident), depth-4 register pipeline.
// C/D layout per m89: col = lane&15, row = (lane>>4)*4 + j.
__device__ __forceinline__ void gemm32g(const bf16_t* a_lds, const bf16_t* __restrict__ Bf,
                                        f32x4 acc[2][2], int lane, int wc)
{
    const int lr = lane & 15, lhi = lane >> 4;
    const bf16_t* bp = Bf + (size_t)wc * 16 * 512 + lane * 8;
    bf16x8 bq0[4], bq1[4];
#pragma unroll
    for (int p = 0; p < 4; ++p) {
        bq0[p] = *(const bf16x8*)&bp[p * 512];
        bq1[p] = *(const bf16x8*)&bp[(8 + p) * 512];
    }
#pragma unroll
    for (int ks = 0; ks < 8; ++ks) {
        const int kc = ks * 32 + lhi * 8;
        bf16x8 af0 = *(const bf16x8*)&a_lds[swz(lr, kc)];
        bf16x8 af1 = *(const bf16x8*)&a_lds[swz(16 + lr, kc)];
        acc[0][0] = __builtin_amdgcn_mfma_f32_16x16x32_bf16(af0, bq0[ks & 3], acc[0][0], 0, 0, 0);
        acc[1][0] = __builtin_amdgcn_mfma_f32_16x16x32_bf16(af1, bq0[ks & 3], acc[1][0], 0, 0, 0);
        acc[0][1] = __builtin_amdgcn_mfma_f32_16x16x32_bf16(af0, bq1[ks & 3], acc[0][1], 0, 0, 0);
        acc[1][1] = __builtin_amdgcn_mfma_f32_16x16x32_bf16(af1, bq1[ks & 3], acc[1][1], 0, 0, 0);
        if (ks + 4 < 8) {
            bq0[ks & 3] = *(const bf16x8*)&bp[(ks + 4) * 512];
            bq1[ks & 3] = *(const bf16x8*)&bp[(8 + ks + 4) * 512];
        }
    }
}

// ---- W_agg [256][512] fp32 -> W1f / W2f fragment layout (bf16).
__global__ void prep_wfrag(const float* __restrict__ W,
                           bf16_t* __restrict__ W1f, bf16_t* __restrict__ W2f)
{
    int t = blockIdx.x * 256 + threadIdx.x;
    int lane = t & 63;
    int ks = (t >> 6) & 7;
    int nt = (t >> 9) & 15;
    int half = t >> 13;
    int row = nt * 16 + (lane & 15);
    int col = ks * 32 + (lane >> 4) * 8;
    const float* src = W + (size_t)row * 512 + half * 256 + col;
    bf16_t* dst = (half ? W2f : W1f) + ((nt * 8 + ks) * 64 + lane) * 8;
    bf16x8 v;
#pragma unroll
    for (int m = 0; m < 8; ++m) v[m] = (bf16_t)src[m];
    *(bf16x8*)dst = v;
}

// ---- P[a][i][j] fp32 -> Pt[a][j][i] bf16 via LDS transpose.
__global__ void transpose_P(const float* __restrict__ Pf, const float* __restrict__ Pb,
                            bf16_t* __restrict__ Pft, bf16_t* __restrict__ Pbt)
{
    __shared__ float t[32][33];
    int blk = blockIdx.x;
    int mat = blk >> 10;
    int rest = blk & 1023;
    int a = rest >> 6;
    int tile = rest & 63;
    int i0 = (tile >> 3) * 32;
    int j0 = (tile & 7) * 32;
    const float* src = (mat ? Pb : Pf) + a * 65536;
    bf16_t* dst = (mat ? Pbt : Pft) + a * 65536;
    int r = threadIdx.x >> 5, c = threadIdx.x & 31;
#pragma unroll
    for (int it = 0; it < 4; ++it)
        t[r + 8 * it][c] = src[(i0 + r + 8 * it) * 256 + j0 + c];
    __syncthreads();
#pragma unroll
    for (int it = 0; it < 4; ++it)
        dst[(j0 + r + 8 * it) * 256 + i0 + c] = (bf16_t)t[c][r + 8 * it];
}

// ---- row-major bf16 [16][256][256] -> fragment layout.
__global__ void prep_pfrag(const bf16_t* __restrict__ Pt, bf16_t* __restrict__ Pfr)
{
    int t = blockIdx.x * 256 + threadIdx.x;
    int lane = t & 63;
    int ks = (t >> 6) & 7;
    int nt = (t >> 9) & 15;
    int a = t >> 13;
    bf16x8 v = *(const bf16x8*)&Pt[(size_t)a * 65536 + (nt * 16 + (lane & 15)) * 256 + ks * 32 + (lane >> 4) * 8];
    *(bf16x8*)&Pfr[(size_t)a * 65536 + ((nt * 8 + ks) * 64 + lane) * 8] = v;
}

// ---- edge [b][a][d] fp32 -> edgeT [a][b][d] bf16 (linear reads).
__global__ void edge_tr(const float* __restrict__ edge, bf16_t* __restrict__ edgeT)
{
    size_t t = (size_t)blockIdx.x * 256 + threadIdx.x;
    size_t b = t >> 9;
    int a = (int)((t >> 5) & 15);
    int d8 = (int)(t & 31);
    const float* src = edge + (b << 12) + (a << 8) + (d8 << 3);
    f32x4 v0 = *(const f32x4*)src;
    f32x4 v1 = *(const f32x4*)(src + 4);
    *(bf16x8*)&edgeT[(((size_t)a << 14) + b) * 256 + (d8 << 3)] = cvt8(v0, v1);
}

// ---- fused main. LDS 64KB, 2 blocks/CU, 2 drain-free barriers per a-iter.
__global__ __launch_bounds__(512, 4)
void fused_main(const float* __restrict__ img, const float* __restrict__ bias,
                const bf16_t* __restrict__ edgeT,
                const bf16_t* __restrict__ W1f, const bf16_t* __restrict__ W2f,
                const bf16_t* __restrict__ Pff, const bf16_t* __restrict__ Pbf,
                const float* __restrict__ sw, float* __restrict__ out)
{
    __shared__ bf16_t E[2][32 * 256];   // 2 x 16 KB edge dbuf
    __shared__ bf16_t G[32 * 256];      // 16 KB agg
    __shared__ bf16_t R[32 * 256];      // 16 KB attr bf16

    const int tid = threadIdx.x;
    const int lane = tid & 63;
    const int wc = tid >> 6;            // 0..7: 32-col slice
    const int lr = lane & 15;
    const int lhi = lane >> 4;
    const int brow0 = blockIdx.x * 32;
    const int sr = tid >> 4;            // staging row 0..31
    const int c16 = (tid & 15) * 16;    // staging col base

    // ---- prologue: img -> E[0] (bf16 swz); full syncs are fine here (once)
    {
        const float* ip = img + (size_t)(brow0 + sr) * ND + c16;
        f32x4 v0 = *(const f32x4*)(ip + 0), v1 = *(const f32x4*)(ip + 4);
        f32x4 v2 = *(const f32x4*)(ip + 8), v3 = *(const f32x4*)(ip + 12);
        *(bf16x8*)&E[0][swz(sr, c16)] = cvt8(v0, v1);
        *(bf16x8*)&E[0][swz(sr, c16 + 8)] = cvt8(v2, v3);
    }
    __syncthreads();

    // ---- T = img @ W1^T + bias (kept in 16 regs; W1 via L2 fragment path)
    f32x4 T[2][2];
#pragma unroll
    for (int ni = 0; ni < 2; ++ni) {
        float bz = bias[wc * 32 + ni * 16 + lr];
        T[0][ni] = (f32x4){bz, bz, bz, bz};
        T[1][ni] = (f32x4){bz, bz, bz, bz};
    }
    gemm32g(&E[0][0], W1f, T, lane, wc);
    __syncthreads();                    // E[0] free

    // ---- edge(a=0) -> E[0] (plain loads: edgeT is L3-resident)
    {
        const bf16_t* ep = edgeT + ((size_t)0 * NB + brow0 + sr) * ND + c16;
        *(bf16x8*)&E[0][swz(sr, c16)] = *(const bf16x8*)ep;
        *(bf16x8*)&E[0][swz(sr, c16 + 8)] = *(const bf16x8*)(ep + 8);
    }
    __syncthreads();

    f32x4 indiv[2][2];
#pragma unroll
    for (int mi = 0; mi < 2; ++mi)
#pragma unroll
        for (int ni = 0; ni < 2; ++ni)
            indiv[mi][ni] = (f32x4){0.f, 0.f, 0.f, 0.f};

    for (int a = 0; a < NA; ++a) {
        const int cur = a & 1;
        const bool pf = (a + 1 < NA);
        f32x4 acc[2][2];

        // ---- phase 1: issue edge(a+1) loads; GEMM1 = T + edge @ W2^T
        bf16x8 elo, ehi;
        if (pf) {
            const bf16_t* ep = edgeT + ((size_t)(a + 1) * NB + brow0 + sr) * ND + c16;
            elo = *(const bf16x8*)ep;
            ehi = *(const bf16x8*)(ep + 8);
        }
#pragma unroll
        for (int mi = 0; mi < 2; ++mi)
#pragma unroll
            for (int ni = 0; ni < 2; ++ni)
                acc[mi][ni] = T[mi][ni];
        gemm32g(&E[cur][0], W2f, acc, lane, wc);
#pragma unroll
        for (int mi = 0; mi < 2; ++mi)
#pragma unroll
            for (int ni = 0; ni < 2; ++ni)
#pragma unroll
                for (int j = 0; j < 4; ++j)
                    G[swz(mi * 16 + lhi * 4 + j, wc * 32 + ni * 16 + lr)] = (bf16_t)acc[mi][ni][j];
        if (pf) {   // commit edge(a+1) (vmcnt for elo/ehi is a counted, data-dep wait)
            *(bf16x8*)&E[cur ^ 1][swz(sr, c16)] = elo;
            *(bf16x8*)&E[cur ^ 1][swz(sr, c16 + 8)] = ehi;
        }
        PHASE_BAR();                    // G + E-commit visible; no vmcnt drain

        // ---- phase 2: attr = agg @ Pf[a] -> R (bf16 swz)
#pragma unroll
        for (int mi = 0; mi < 2; ++mi)
#pragma unroll
            for (int ni = 0; ni < 2; ++ni)
                acc[mi][ni] = (f32x4){0.f, 0.f, 0.f, 0.f};
        gemm32g(&G[0], Pff + (size_t)a * 65536, acc, lane, wc);
#pragma unroll
        for (int mi = 0; mi < 2; ++mi)
#pragma unroll
            for (int ni = 0; ni < 2; ++ni)
#pragma unroll
                for (int j = 0; j < 4; ++j)
                    R[swz(mi * 16 + lhi * 4 + j, wc * 32 + ni * 16 + lr)] = (bf16_t)acc[mi][ni][j];
        PHASE_BAR();                    // R visible; no vmcnt drain

        // ---- phase 3: GEMM3 proj = relu(attr @ Pb[a]); indiv += proj*sw;
        //      then attr readback -> plain full-line fp32 stores (retire at L2,
        //      age across next phase's MFMA work). NO barrier at phase end:
        //      next write to R/G/E is behind the next iteration's barriers.
#pragma unroll
        for (int mi = 0; mi < 2; ++mi)
#pragma unroll
            for (int ni = 0; ni < 2; ++ni)
                acc[mi][ni] = (f32x4){0.f, 0.f, 0.f, 0.f};
        gemm32g(&R[0], Pbf + (size_t)a * 65536, acc, lane, wc);
        const float swa = sw[a];
#pragma unroll
        for (int mi = 0; mi < 2; ++mi)
#pragma unroll
            for (int ni = 0; ni < 2; ++ni)
#pragma unroll
                for (int j = 0; j < 4; ++j)
                    indiv[mi][ni][j] += fmaxf(acc[mi][ni][j], 0.f) * swa;
        {
            float* op = out + (size_t)brow0 * (NA * ND) + (size_t)a * ND;
#pragma unroll
            for (int h = 0; h < 2; ++h) {
                int r = (tid >> 5) + h * 16;
                int ce = (tid & 31) * 8;
                bf16x8 v = *(const bf16x8*)&R[swz(r, ce)];
                f32x4 lo = {(float)v[0], (float)v[1], (float)v[2], (float)v[3]};
                f32x4 hi = {(float)v[4], (float)v[5], (float)v[6], (float)v[7]};
                float* p = op + (size_t)r * (NA * ND) + ce;
                *(f32x4*)p = lo;
                *(f32x4*)(p + 4) = hi;
            }
        }
    }

    // ---- individual_embeddings (plain stores)
#pragma unroll
    for (int mi = 0; mi < 2; ++mi)
#pragma unroll
        for (int ni = 0; ni < 2; ++ni)
#pragma unroll
            for (int j = 0; j < 4; ++j) {
                int r = mi * 16 + lhi * 4 + j;
                int c = wc * 32 + ni * 16 + lr;
                out[(size_t)NB * NA * ND + (size_t)(brow0 + r) * ND + c] = indiv[mi][ni][j];
            }
}

extern "C" void kernel_launch(void* const* d_in, const int* in_sizes, int n_in,
                              void* d_out, int out_size, void* d_ws, size_t ws_size,
                              hipStream_t stream)
{
    const float* img  = (const float*)d_in[0];
    const float* edge = (const float*)d_in[1];
    const float* Wagg = (const float*)d_in[2];
    const float* bagg = (const float*)d_in[3];
    const float* Pf   = (const float*)d_in[4];
    const float* Pb   = (const float*)d_in[5];
    const float* sw   = (const float*)d_in[6];
    float* out = (float*)d_out;

    char* ws = (char*)d_ws;
    bf16_t* W1f = (bf16_t*)(ws);                   // 128 KB fragment layout
    bf16_t* W2f = (bf16_t*)(ws + 131072);          // 128 KB
    bf16_t* Pff = (bf16_t*)(ws + 262144);          // 2 MB
    bf16_t* Pbf = (bf16_t*)(ws + 2359296);         // 2 MB
    bf16_t* edT = (bf16_t*)(ws + 4456448);         // 134.2 MB [a][b][d] bf16
    // temps alias edT (dead before edge_tr runs; stream-ordered)
    bf16_t* Ptf = (bf16_t*)(ws + 4456448);         // 2 MB row-major temp
    bf16_t* Ptb = (bf16_t*)(ws + 6553600);         // 2 MB row-major temp

    prep_wfrag<<<64, 256, 0, stream>>>(Wagg, W1f, W2f);
    transpose_P<<<2048, 256, 0, stream>>>(Pf, Pb, Ptf, Ptb);
    prep_pfrag<<<512, 256, 0, stream>>>(Ptf, Pff);
    prep_pfrag<<<512, 256, 0, stream>>>(Ptb, Pbf);
    edge_tr<<<32768, 256, 0, stream>>>(edge, edT);
    fused_main<<<NB / 32, 512, 0, stream>>>(img, bagg, edT, W1f, W2f, Pff, Pbf, sw, out);
}

// Round 15
// 386.097 us; speedup vs baseline: 1.5171x; 1.4276x over previous
//
#include <hip/hip_runtime.h>
#include <hip/hip_bf16.h>

// AttributeGNN, bf16 MFMA, fp32 accumulate. B=16384, A=16, D=256.
// R15: R14 (B-in-registers, M-subtiled, BM=64, 256 blocks -> weight traffic
// 3.0GB -> 1.57GB; confirmed fast at 366us replay) with the racy hand-rolled
// drain-free barriers replaced by __syncthreads(). Raw s_barrier is NOT an
// LLVM memory fence -> with E/G aliased in one LDS buffer the read->bar->write
// pattern raced under graph replay (R14 post-timing absmax 5.0). The vmcnt
// drain __syncthreads adds costs ~3% (measured R12->R13) - paid for safety.

typedef __bf16 bf16_t;
typedef __bf16 bf16x4 __attribute__((ext_vector_type(4)));
typedef __bf16 bf16x8 __attribute__((ext_vector_type(8)));
typedef float f32x4 __attribute__((ext_vector_type(4)));

#define NB 16384
#define NA 16
#define ND 256
#define BM 64

// XOR swizzle for bf16 LDS tiles [*][256]: slot = chunk ^ (row&15), full
// permutation over 32 8-elem chunks -> conflict-free A-reads.
__device__ __forceinline__ int swz(int r, int c) {
    return r * 256 + (c ^ ((r & 15) << 3));
}

__device__ __forceinline__ bf16x8 cvt8(f32x4 a, f32x4 b) {
    bf16x8 r;
    r[0] = (bf16_t)a.x; r[1] = (bf16_t)a.y; r[2] = (bf16_t)a.z; r[3] = (bf16_t)a.w;
    r[4] = (bf16_t)b.x; r[5] = (bf16_t)b.y; r[6] = (bf16_t)b.z; r[7] = (bf16_t)b.w;
    return r;
}

// ---- W_agg [256][512] fp32 -> W1f / W2f fragment layout (bf16).
__global__ void prep_wfrag(const float* __restrict__ W,
                           bf16_t* __restrict__ W1f, bf16_t* __restrict__ W2f)
{
    int t = blockIdx.x * 256 + threadIdx.x;
    int lane = t & 63;
    int ks = (t >> 6) & 7;
    int nt = (t >> 9) & 15;
    int half = t >> 13;
    int row = nt * 16 + (lane & 15);
    int col = ks * 32 + (lane >> 4) * 8;
    const float* src = W + (size_t)row * 512 + half * 256 + col;
    bf16_t* dst = (half ? W2f : W1f) + ((nt * 8 + ks) * 64 + lane) * 8;
    bf16x8 v;
#pragma unroll
    for (int m = 0; m < 8; ++m) v[m] = (bf16_t)src[m];
    *(bf16x8*)dst = v;
}

// ---- P[a][i][j] fp32 -> Pt[a][j][i] bf16 via LDS transpose.
__global__ void transpose_P(const float* __restrict__ Pf, const float* __restrict__ Pb,
                            bf16_t* __restrict__ Pft, bf16_t* __restrict__ Pbt)
{
    __shared__ float t[32][33];
    int blk = blockIdx.x;
    int mat = blk >> 10;
    int rest = blk & 1023;
    int a = rest >> 6;
    int tile = rest & 63;
    int i0 = (tile >> 3) * 32;
    int j0 = (tile & 7) * 32;
    const float* src = (mat ? Pb : Pf) + a * 65536;
    bf16_t* dst = (mat ? Pbt : Pft) + a * 65536;
    int r = threadIdx.x >> 5, c = threadIdx.x & 31;
#pragma unroll
    for (int it = 0; it < 4; ++it)
        t[r + 8 * it][c] = src[(i0 + r + 8 * it) * 256 + j0 + c];
    __syncthreads();
#pragma unroll
    for (int it = 0; it < 4; ++it)
        dst[(j0 + r + 8 * it) * 256 + i0 + c] = (bf16_t)t[c][r + 8 * it];
}

// ---- row-major bf16 [16][256][256] -> fragment layout.
__global__ void prep_pfrag(const bf16_t* __restrict__ Pt, bf16_t* __restrict__ Pfr)
{
    int t = blockIdx.x * 256 + threadIdx.x;
    int lane = t & 63;
    int ks = (t >> 6) & 7;
    int nt = (t >> 9) & 15;
    int a = t >> 13;
    bf16x8 v = *(const bf16x8*)&Pt[(size_t)a * 65536 + (nt * 16 + (lane & 15)) * 256 + ks * 32 + (lane >> 4) * 8];
    *(bf16x8*)&Pfr[(size_t)a * 65536 + ((nt * 8 + ks) * 64 + lane) * 8] = v;
}

// ---- edge [b][a][d] fp32 -> edgeT [a][b][d] bf16 (linear reads).
__global__ void edge_tr(const float* __restrict__ edge, bf16_t* __restrict__ edgeT)
{
    size_t t = (size_t)blockIdx.x * 256 + threadIdx.x;
    size_t b = t >> 9;
    int a = (int)((t >> 5) & 15);
    int d8 = (int)(t & 31);
    const float* src = edge + (b << 12) + (a << 8) + (d8 << 3);
    f32x4 v0 = *(const f32x4*)src;
    f32x4 v1 = *(const f32x4*)(src + 4);
    *(bf16x8*)&edgeT[(((size_t)a << 14) + b) * 256 + (d8 << 3)] = cvt8(v0, v1);
}

// ---- fused main. 256 blocks x 512 thr, 1 block/CU, LDS 128KB.
__global__ __launch_bounds__(512, 2)
void fused_main(const float* __restrict__ img, const float* __restrict__ bias,
                const bf16_t* __restrict__ edgeT,
                const bf16_t* __restrict__ W1f, const bf16_t* __restrict__ W2f,
                const bf16_t* __restrict__ Pff, const bf16_t* __restrict__ Pbf,
                const float* __restrict__ sw, float* __restrict__ out)
{
    __shared__ bf16_t EG[BM * 256];     // 32 KB: edge tile, then G (agg), alternating
    __shared__ bf16_t Rl[BM * 256];     // 32 KB: attr bf16
    __shared__ float  Tl[BM * 256];     // 64 KB: T = img@W1^T + bias (a-invariant)

    const int tid = threadIdx.x;
    const int lane = tid & 63;
    const int wc = tid >> 6;            // 0..7: 32-col N-slice
    const int lr = lane & 15;
    const int lhi = lane >> 4;
    const int brow0 = blockIdx.x * BM;
    const int sr = tid >> 3;            // staging row 0..63
    const int scb = (tid & 7) * 32;     // staging col base (32 elems)

    bf16x8 B[2][8];                     // wave's B-slice: 16 frags = 64 VGPR

#define LOADB(MAT) do {                                                       \
    const bf16_t* bp_ = (MAT) + (size_t)wc * 16 * 512 + lane * 8;             \
    _Pragma("unroll") for (int ni_ = 0; ni_ < 2; ++ni_)                       \
    _Pragma("unroll") for (int ks_ = 0; ks_ < 8; ++ks_)                       \
        B[ni_][ks_] = *(const bf16x8*)&bp_[(ni_ * 8 + ks_) * 512];            \
} while (0)

// One 32-row subtile GEMM: A from LDS SRC (swizzled), B from regs. Zero vmem.
#define SUBGEMM(SRC, IB, ACC) do {                                            \
    _Pragma("unroll") for (int ks_ = 0; ks_ < 8; ++ks_) {                     \
        const int kc_ = ks_ * 32 + lhi * 8;                                   \
        bf16x8 af0_ = *(const bf16x8*)&(SRC)[swz((IB) * 32 + lr, kc_)];       \
        bf16x8 af1_ = *(const bf16x8*)&(SRC)[swz((IB) * 32 + 16 + lr, kc_)];  \
        ACC[0][0] = __builtin_amdgcn_mfma_f32_16x16x32_bf16(af0_, B[0][ks_], ACC[0][0], 0, 0, 0); \
        ACC[1][0] = __builtin_amdgcn_mfma_f32_16x16x32_bf16(af1_, B[0][ks_], ACC[1][0], 0, 0, 0); \
        ACC[0][1] = __builtin_amdgcn_mfma_f32_16x16x32_bf16(af0_, B[1][ks_], ACC[0][1], 0, 0, 0); \
        ACC[1][1] = __builtin_amdgcn_mfma_f32_16x16x32_bf16(af1_, B[1][ks_], ACC[1][1], 0, 0, 0); \
    }                                                                         \
} while (0)

// C-scatter to LDS (bf16, swizzled), subtile IB.
#define WRITEC(DST, IB, ACC) do {                                             \
    _Pragma("unroll") for (int mi_ = 0; mi_ < 2; ++mi_)                       \
    _Pragma("unroll") for (int ni_ = 0; ni_ < 2; ++ni_)                       \
    _Pragma("unroll") for (int j_ = 0; j_ < 4; ++j_)                          \
        (DST)[swz((IB) * 32 + mi_ * 16 + lhi * 4 + j_, wc * 32 + ni_ * 16 + lr)] = (bf16_t)ACC[mi_][ni_][j_]; \
} while (0)

    // ---- prologue: stage img -> EG (bf16 swz)
    {
        const float* ip = img + (size_t)(brow0 + sr) * ND + scb;
#pragma unroll
        for (int q = 0; q < 4; ++q) {
            f32x4 v0 = *(const f32x4*)(ip + q * 8);
            f32x4 v1 = *(const f32x4*)(ip + q * 8 + 4);
            *(bf16x8*)&EG[swz(sr, scb + q * 8)] = cvt8(v0, v1);
        }
    }
    __syncthreads();

    // ---- T = img @ W1^T + bias -> Tl (fp32 LDS)
    f32x4 acc0[2][2], acc1[2][2];
    {
        LOADB(W1f);
#pragma unroll
        for (int ni = 0; ni < 2; ++ni) {
            float bz = bias[wc * 32 + ni * 16 + lr];
            acc0[0][ni] = (f32x4){bz, bz, bz, bz}; acc0[1][ni] = (f32x4){bz, bz, bz, bz};
            acc1[0][ni] = (f32x4){bz, bz, bz, bz}; acc1[1][ni] = (f32x4){bz, bz, bz, bz};
        }
        SUBGEMM(EG, 0, acc0);
        SUBGEMM(EG, 1, acc1);
#pragma unroll
        for (int mi = 0; mi < 2; ++mi)
#pragma unroll
            for (int ni = 0; ni < 2; ++ni)
#pragma unroll
                for (int j = 0; j < 4; ++j) {
                    int c = wc * 32 + ni * 16 + lr;
                    Tl[(mi * 16 + lhi * 4 + j) * 256 + c] = acc0[mi][ni][j];
                    Tl[(32 + mi * 16 + lhi * 4 + j) * 256 + c] = acc1[mi][ni][j];
                }
    }
    __syncthreads();

    // ---- stage edge(a=0) -> EG
    {
        const bf16_t* ep = edgeT + ((size_t)0 * NB + brow0 + sr) * ND + scb;
#pragma unroll
        for (int q = 0; q < 4; ++q)
            *(bf16x8*)&EG[swz(sr, scb + q * 8)] = *(const bf16x8*)(ep + q * 8);
    }
    __syncthreads();

    f32x4 indiv[2][2][2];
#pragma unroll
    for (int i = 0; i < 2; ++i)
#pragma unroll
        for (int mi = 0; mi < 2; ++mi)
#pragma unroll
            for (int ni = 0; ni < 2; ++ni)
                indiv[i][mi][ni] = (f32x4){0.f, 0.f, 0.f, 0.f};

    for (int a = 0; a < NA; ++a) {
        // ---- P1: agg = T + edge @ W2^T (B=W2 regs, A=EG, C->EG as G)
        LOADB(W2f);
#pragma unroll
        for (int mi = 0; mi < 2; ++mi)
#pragma unroll
            for (int ni = 0; ni < 2; ++ni)
#pragma unroll
                for (int j = 0; j < 4; ++j) {
                    int c = wc * 32 + ni * 16 + lr;
                    acc0[mi][ni][j] = Tl[(mi * 16 + lhi * 4 + j) * 256 + c];
                    acc1[mi][ni][j] = Tl[(32 + mi * 16 + lhi * 4 + j) * 256 + c];
                }
        SUBGEMM(EG, 0, acc0);
        SUBGEMM(EG, 1, acc1);
        __syncthreads();                // all EG (edge) reads complete block-wide
        WRITEC(EG, 0, acc0);            // overwrite EG with G
        WRITEC(EG, 1, acc1);
        __syncthreads();                // G visible

        // ---- P2: attr = G @ Pf[a] -> Rl
        LOADB(Pff + (size_t)a * 65536);
#pragma unroll
        for (int mi = 0; mi < 2; ++mi)
#pragma unroll
            for (int ni = 0; ni < 2; ++ni) {
                acc0[mi][ni] = (f32x4){0.f, 0.f, 0.f, 0.f};
                acc1[mi][ni] = (f32x4){0.f, 0.f, 0.f, 0.f};
            }
        SUBGEMM(EG, 0, acc0);
        SUBGEMM(EG, 1, acc1);
        WRITEC(Rl, 0, acc0);
        WRITEC(Rl, 1, acc1);
        __syncthreads();                // Rl visible; EG reads complete

        // ---- P3: Pb loads; attr stores from Rl; GEMM3 -> indiv; edge(a+1) -> EG
        LOADB(Pbf + (size_t)a * 65536);
        {   // full-line fp32 attr stores (read Rl, convert)
            float* op = out + (size_t)(brow0 + sr) * (NA * ND) + (size_t)a * ND + scb;
#pragma unroll
            for (int q = 0; q < 4; ++q) {
                bf16x8 v = *(const bf16x8*)&Rl[swz(sr, scb + q * 8)];
                f32x4 lo = {(float)v[0], (float)v[1], (float)v[2], (float)v[3]};
                f32x4 hi = {(float)v[4], (float)v[5], (float)v[6], (float)v[7]};
                *(f32x4*)(op + q * 8) = lo;
                *(f32x4*)(op + q * 8 + 4) = hi;
            }
        }
#pragma unroll
        for (int mi = 0; mi < 2; ++mi)
#pragma unroll
            for (int ni = 0; ni < 2; ++ni) {
                acc0[mi][ni] = (f32x4){0.f, 0.f, 0.f, 0.f};
                acc1[mi][ni] = (f32x4){0.f, 0.f, 0.f, 0.f};
            }
        SUBGEMM(Rl, 0, acc0);
        SUBGEMM(Rl, 1, acc1);
        const float swa = sw[a];
#pragma unroll
        for (int mi = 0; mi < 2; ++mi)
#pragma unroll
            for (int ni = 0; ni < 2; ++ni)
#pragma unroll
                for (int j = 0; j < 4; ++j) {
                    indiv[0][mi][ni][j] += fmaxf(acc0[mi][ni][j], 0.f) * swa;
                    indiv[1][mi][ni][j] += fmaxf(acc1[mi][ni][j], 0.f) * swa;
                }
        if (a + 1 < NA) {               // stage edge(a+1) into EG (G consumed)
            const bf16_t* ep = edgeT + ((size_t)(a + 1) * NB + brow0 + sr) * ND + scb;
            bf16x8 e0 = *(const bf16x8*)(ep + 0);
            bf16x8 e1 = *(const bf16x8*)(ep + 8);
            bf16x8 e2 = *(const bf16x8*)(ep + 16);
            bf16x8 e3 = *(const bf16x8*)(ep + 24);
            *(bf16x8*)&EG[swz(sr, scb + 0)] = e0;
            *(bf16x8*)&EG[swz(sr, scb + 8)] = e1;
            *(bf16x8*)&EG[swz(sr, scb + 16)] = e2;
            *(bf16x8*)&EG[swz(sr, scb + 24)] = e3;
        }
        __syncthreads();                // edge(a+1) visible; Rl reads complete
    }

    // ---- individual_embeddings
#pragma unroll
    for (int i = 0; i < 2; ++i)
#pragma unroll
        for (int mi = 0; mi < 2; ++mi)
#pragma unroll
            for (int ni = 0; ni < 2; ++ni)
#pragma unroll
                for (int j = 0; j < 4; ++j) {
                    int r = i * 32 + mi * 16 + lhi * 4 + j;
                    int c = wc * 32 + ni * 16 + lr;
                    out[(size_t)NB * NA * ND + (size_t)(brow0 + r) * ND + c] = indiv[i][mi][ni][j];
                }
#undef LOADB
#undef SUBGEMM
#undef WRITEC
}

extern "C" void kernel_launch(void* const* d_in, const int* in_sizes, int n_in,
                              void* d_out, int out_size, void* d_ws, size_t ws_size,
                              hipStream_t stream)
{
    const float* img  = (const float*)d_in[0];
    const float* edge = (const float*)d_in[1];
    const float* Wagg = (const float*)d_in[2];
    const float* bagg = (const float*)d_in[3];
    const float* Pf   = (const float*)d_in[4];
    const float* Pb   = (const float*)d_in[5];
    const float* sw   = (const float*)d_in[6];
    float* out = (float*)d_out;

    char* ws = (char*)d_ws;
    bf16_t* W1f = (bf16_t*)(ws);                   // 128 KB fragment layout
    bf16_t* W2f = (bf16_t*)(ws + 131072);          // 128 KB
    bf16_t* Pff = (bf16_t*)(ws + 262144);          // 2 MB
    bf16_t* Pbf = (bf16_t*)(ws + 2359296);         // 2 MB
    bf16_t* edT = (bf16_t*)(ws + 4456448);         // 134.2 MB [a][b][d] bf16
    // temps alias edT (dead before edge_tr runs; stream-ordered)
    bf16_t* Ptf = (bf16_t*)(ws + 4456448);         // 2 MB row-major temp
    bf16_t* Ptb = (bf16_t*)(ws + 6553600);         // 2 MB row-major temp

    prep_wfrag<<<64, 256, 0, stream>>>(Wagg, W1f, W2f);
    transpose_P<<<2048, 256, 0, stream>>>(Pf, Pb, Ptf, Ptb);
    prep_pfrag<<<512, 256, 0, stream>>>(Ptf, Pff);
    prep_pfrag<<<512, 256, 0, stream>>>(Ptb, Pbf);
    edge_tr<<<32768, 256, 0, stream>>>(edge, edT);
    fused_main<<<NB / BM, 512, 0, stream>>>(img, bagg, edT, W1f, W2f, Pff, Pbf, sw, out);
}

// Round 16
// 304.115 us; speedup vs baseline: 1.9261x; 1.2696x over previous
//
#include <hip/hip_runtime.h>
#include <hip/hip_bf16.h>

// AttributeGNN, bf16 MFMA, fp32 accumulate. B=16384, A=16, D=256.
// R16: prep-chain elimination on top of R15 (B-in-regs M-subtiled core, 272us):
//  - edge_tr DELETED: fused_main reads edge [b][a][d] fp32 directly (1KB
//    contiguous per row per a, 16KB stride) - net -268MB HBM + one less pass.
//  - transpose_P + prep_pfrag fused into prep_pfrag2 (fp32 P -> fragment
//    layout in one kernel, one wave per fragment).
//  - fused_main core identical to R15 (syncthreads barriers, proven correct).

typedef __bf16 bf16_t;
typedef __bf16 bf16x4 __attribute__((ext_vector_type(4)));
typedef __bf16 bf16x8 __attribute__((ext_vector_type(8)));
typedef float f32x4 __attribute__((ext_vector_type(4)));

#define NB 16384
#define NA 16
#define ND 256
#define BM 64

// XOR swizzle for bf16 LDS tiles [*][256]: slot = chunk ^ (row&15), full
// permutation over 32 8-elem chunks -> conflict-free A-reads.
__device__ __forceinline__ int swz(int r, int c) {
    return r * 256 + (c ^ ((r & 15) << 3));
}

__device__ __forceinline__ bf16x8 cvt8(f32x4 a, f32x4 b) {
    bf16x8 r;
    r[0] = (bf16_t)a.x; r[1] = (bf16_t)a.y; r[2] = (bf16_t)a.z; r[3] = (bf16_t)a.w;
    r[4] = (bf16_t)b.x; r[5] = (bf16_t)b.y; r[6] = (bf16_t)b.z; r[7] = (bf16_t)b.w;
    return r;
}

// ---- W_agg [256][512] fp32 -> W1f / W2f fragment layout (bf16).
__global__ void prep_wfrag(const float* __restrict__ W,
                           bf16_t* __restrict__ W1f, bf16_t* __restrict__ W2f)
{
    int t = blockIdx.x * 256 + threadIdx.x;
    int lane = t & 63;
    int ks = (t >> 6) & 7;
    int nt = (t >> 9) & 15;
    int half = t >> 13;
    int row = nt * 16 + (lane & 15);
    int col = ks * 32 + (lane >> 4) * 8;
    const float* src = W + (size_t)row * 512 + half * 256 + col;
    bf16_t* dst = (half ? W2f : W1f) + ((nt * 8 + ks) * 64 + lane) * 8;
    bf16x8 v;
#pragma unroll
    for (int m = 0; m < 8; ++m) v[m] = (bf16_t)src[m];
    *(bf16x8*)dst = v;
}

// ---- P[a][i][j] fp32 -> fragment layout of P^T directly (one wave / frag).
// Fragment f=(nt*8+ks), lane l, elem m = P^T[nt*16+(l&15)][ks*32+(l>>4)*8+m]
//                                      = P[ks*32+(l>>4)*8+m][nt*16+(l&15)].
__global__ void prep_pfrag2(const float* __restrict__ Pf, const float* __restrict__ Pb,
                            bf16_t* __restrict__ Pff, bf16_t* __restrict__ Pbf)
{
    int gw = (blockIdx.x * 256 + threadIdx.x) >> 6;   // 0..4095
    int lane = threadIdx.x & 63;
    int frag = gw & 127;
    int a = (gw >> 7) & 15;
    int mat = gw >> 11;
    int nt = frag >> 3, ks = frag & 7;
    const float* src = (mat ? Pb : Pf) + (size_t)a * 65536;
    bf16_t* dst = (mat ? Pbf : Pff) + (size_t)a * 65536 + ((size_t)frag * 64 + lane) * 8;
    int i0 = ks * 32 + (lane >> 4) * 8;
    int j = nt * 16 + (lane & 15);
    bf16x8 v;
#pragma unroll
    for (int m = 0; m < 8; ++m)
        v[m] = (bf16_t)src[(size_t)(i0 + m) * 256 + j];
    *(bf16x8*)dst = v;
}

// ---- fused main. 256 blocks x 512 thr, 1 block/CU, LDS 128KB.
__global__ __launch_bounds__(512, 2)
void fused_main(const float* __restrict__ img, const float* __restrict__ bias,
                const float* __restrict__ edge,
                const bf16_t* __restrict__ W1f, const bf16_t* __restrict__ W2f,
                const bf16_t* __restrict__ Pff, const bf16_t* __restrict__ Pbf,
                const float* __restrict__ sw, float* __restrict__ out)
{
    __shared__ bf16_t EG[BM * 256];     // 32 KB: edge tile, then G (agg), alternating
    __shared__ bf16_t Rl[BM * 256];     // 32 KB: attr bf16
    __shared__ float  Tl[BM * 256];     // 64 KB: T = img@W1^T + bias (a-invariant)

    const int tid = threadIdx.x;
    const int lane = tid & 63;
    const int wc = tid >> 6;            // 0..7: 32-col N-slice
    const int lr = lane & 15;
    const int lhi = lane >> 4;
    const int brow0 = blockIdx.x * BM;
    const int sr = tid >> 3;            // staging row 0..63
    const int scb = (tid & 7) * 32;     // staging col base (32 elems)

    bf16x8 B[2][8];                     // wave's B-slice: 16 frags = 64 VGPR

#define LOADB(MAT) do {                                                       \
    const bf16_t* bp_ = (MAT) + (size_t)wc * 16 * 512 + lane * 8;             \
    _Pragma("unroll") for (int ni_ = 0; ni_ < 2; ++ni_)                       \
    _Pragma("unroll") for (int ks_ = 0; ks_ < 8; ++ks_)                       \
        B[ni_][ks_] = *(const bf16x8*)&bp_[(ni_ * 8 + ks_) * 512];            \
} while (0)

// One 32-row subtile GEMM: A from LDS SRC (swizzled), B from regs. Zero vmem.
#define SUBGEMM(SRC, IB, ACC) do {                                            \
    _Pragma("unroll") for (int ks_ = 0; ks_ < 8; ++ks_) {                     \
        const int kc_ = ks_ * 32 + lhi * 8;                                   \
        bf16x8 af0_ = *(const bf16x8*)&(SRC)[swz((IB) * 32 + lr, kc_)];       \
        bf16x8 af1_ = *(const bf16x8*)&(SRC)[swz((IB) * 32 + 16 + lr, kc_)];  \
        ACC[0][0] = __builtin_amdgcn_mfma_f32_16x16x32_bf16(af0_, B[0][ks_], ACC[0][0], 0, 0, 0); \
        ACC[1][0] = __builtin_amdgcn_mfma_f32_16x16x32_bf16(af1_, B[0][ks_], ACC[1][0], 0, 0, 0); \
        ACC[0][1] = __builtin_amdgcn_mfma_f32_16x16x32_bf16(af0_, B[1][ks_], ACC[0][1], 0, 0, 0); \
        ACC[1][1] = __builtin_amdgcn_mfma_f32_16x16x32_bf16(af1_, B[1][ks_], ACC[1][1], 0, 0, 0); \
    }                                                                         \
} while (0)

// C-scatter to LDS (bf16, swizzled), subtile IB.
#define WRITEC(DST, IB, ACC) do {                                             \
    _Pragma("unroll") for (int mi_ = 0; mi_ < 2; ++mi_)                       \
    _Pragma("unroll") for (int ni_ = 0; ni_ < 2; ++ni_)                       \
    _Pragma("unroll") for (int j_ = 0; j_ < 4; ++j_)                          \
        (DST)[swz((IB) * 32 + mi_ * 16 + lhi * 4 + j_, wc * 32 + ni_ * 16 + lr)] = (bf16_t)ACC[mi_][ni_][j_]; \
} while (0)

// Stage edge[brow0+sr][A_][scb..scb+31] (fp32, 128B/thread contiguous) -> EG bf16 swz.
#define STAGE_EDGE(A_) do {                                                   \
    const float* ep_ = edge + ((size_t)(brow0 + sr) * NA + (A_)) * ND + scb;  \
    f32x4 w0 = *(const f32x4*)(ep_ + 0),  w1 = *(const f32x4*)(ep_ + 4);      \
    f32x4 w2 = *(const f32x4*)(ep_ + 8),  w3 = *(const f32x4*)(ep_ + 12);     \
    f32x4 w4 = *(const f32x4*)(ep_ + 16), w5 = *(const f32x4*)(ep_ + 20);     \
    f32x4 w6 = *(const f32x4*)(ep_ + 24), w7 = *(const f32x4*)(ep_ + 28);     \
    *(bf16x8*)&EG[swz(sr, scb + 0)]  = cvt8(w0, w1);                          \
    *(bf16x8*)&EG[swz(sr, scb + 8)]  = cvt8(w2, w3);                          \
    *(bf16x8*)&EG[swz(sr, scb + 16)] = cvt8(w4, w5);                          \
    *(bf16x8*)&EG[swz(sr, scb + 24)] = cvt8(w6, w7);                          \
} while (0)

    // ---- prologue: stage img -> EG (bf16 swz)
    {
        const float* ip = img + (size_t)(brow0 + sr) * ND + scb;
#pragma unroll
        for (int q = 0; q < 4; ++q) {
            f32x4 v0 = *(const f32x4*)(ip + q * 8);
            f32x4 v1 = *(const f32x4*)(ip + q * 8 + 4);
            *(bf16x8*)&EG[swz(sr, scb + q * 8)] = cvt8(v0, v1);
        }
    }
    __syncthreads();

    // ---- T = img @ W1^T + bias -> Tl (fp32 LDS)
    f32x4 acc0[2][2], acc1[2][2];
    {
        LOADB(W1f);
#pragma unroll
        for (int ni = 0; ni < 2; ++ni) {
            float bz = bias[wc * 32 + ni * 16 + lr];
            acc0[0][ni] = (f32x4){bz, bz, bz, bz}; acc0[1][ni] = (f32x4){bz, bz, bz, bz};
            acc1[0][ni] = (f32x4){bz, bz, bz, bz}; acc1[1][ni] = (f32x4){bz, bz, bz, bz};
        }
        SUBGEMM(EG, 0, acc0);
        SUBGEMM(EG, 1, acc1);
#pragma unroll
        for (int mi = 0; mi < 2; ++mi)
#pragma unroll
            for (int ni = 0; ni < 2; ++ni)
#pragma unroll
                for (int j = 0; j < 4; ++j) {
                    int c = wc * 32 + ni * 16 + lr;
                    Tl[(mi * 16 + lhi * 4 + j) * 256 + c] = acc0[mi][ni][j];
                    Tl[(32 + mi * 16 + lhi * 4 + j) * 256 + c] = acc1[mi][ni][j];
                }
    }
    __syncthreads();

    // ---- stage edge(a=0) -> EG (direct from [b][a][d] fp32)
    STAGE_EDGE(0);
    __syncthreads();

    f32x4 indiv[2][2][2];
#pragma unroll
    for (int i = 0; i < 2; ++i)
#pragma unroll
        for (int mi = 0; mi < 2; ++mi)
#pragma unroll
            for (int ni = 0; ni < 2; ++ni)
                indiv[i][mi][ni] = (f32x4){0.f, 0.f, 0.f, 0.f};

    for (int a = 0; a < NA; ++a) {
        // ---- P1: agg = T + edge @ W2^T (B=W2 regs, A=EG, C->EG as G)
        LOADB(W2f);
#pragma unroll
        for (int mi = 0; mi < 2; ++mi)
#pragma unroll
            for (int ni = 0; ni < 2; ++ni)
#pragma unroll
                for (int j = 0; j < 4; ++j) {
                    int c = wc * 32 + ni * 16 + lr;
                    acc0[mi][ni][j] = Tl[(mi * 16 + lhi * 4 + j) * 256 + c];
                    acc1[mi][ni][j] = Tl[(32 + mi * 16 + lhi * 4 + j) * 256 + c];
                }
        SUBGEMM(EG, 0, acc0);
        SUBGEMM(EG, 1, acc1);
        __syncthreads();                // all EG (edge) reads complete block-wide
        WRITEC(EG, 0, acc0);            // overwrite EG with G
        WRITEC(EG, 1, acc1);
        __syncthreads();                // G visible

        // ---- P2: attr = G @ Pf[a] -> Rl
        LOADB(Pff + (size_t)a * 65536);
#pragma unroll
        for (int mi = 0; mi < 2; ++mi)
#pragma unroll
            for (int ni = 0; ni < 2; ++ni) {
                acc0[mi][ni] = (f32x4){0.f, 0.f, 0.f, 0.f};
                acc1[mi][ni] = (f32x4){0.f, 0.f, 0.f, 0.f};
            }
        SUBGEMM(EG, 0, acc0);
        SUBGEMM(EG, 1, acc1);
        WRITEC(Rl, 0, acc0);
        WRITEC(Rl, 1, acc1);
        __syncthreads();                // Rl visible; EG reads complete

        // ---- P3: Pb loads; attr stores from Rl; GEMM3 -> indiv; edge(a+1) -> EG
        LOADB(Pbf + (size_t)a * 65536);
        {   // full-line fp32 attr stores (read Rl, convert)
            float* op = out + (size_t)(brow0 + sr) * (NA * ND) + (size_t)a * ND + scb;
#pragma unroll
            for (int q = 0; q < 4; ++q) {
                bf16x8 v = *(const bf16x8*)&Rl[swz(sr, scb + q * 8)];
                f32x4 lo = {(float)v[0], (float)v[1], (float)v[2], (float)v[3]};
                f32x4 hi = {(float)v[4], (float)v[5], (float)v[6], (float)v[7]};
                *(f32x4*)(op + q * 8) = lo;
                *(f32x4*)(op + q * 8 + 4) = hi;
            }
        }
#pragma unroll
        for (int mi = 0; mi < 2; ++mi)
#pragma unroll
            for (int ni = 0; ni < 2; ++ni) {
                acc0[mi][ni] = (f32x4){0.f, 0.f, 0.f, 0.f};
                acc1[mi][ni] = (f32x4){0.f, 0.f, 0.f, 0.f};
            }
        SUBGEMM(Rl, 0, acc0);
        SUBGEMM(Rl, 1, acc1);
        const float swa = sw[a];
#pragma unroll
        for (int mi = 0; mi < 2; ++mi)
#pragma unroll
            for (int ni = 0; ni < 2; ++ni)
#pragma unroll
                for (int j = 0; j < 4; ++j) {
                    indiv[0][mi][ni][j] += fmaxf(acc0[mi][ni][j], 0.f) * swa;
                    indiv[1][mi][ni][j] += fmaxf(acc1[mi][ni][j], 0.f) * swa;
                }
        if (a + 1 < NA) {               // stage edge(a+1) into EG (G consumed)
            STAGE_EDGE(a + 1);
        }
        __syncthreads();                // edge(a+1) visible; Rl reads complete
    }

    // ---- individual_embeddings
#pragma unroll
    for (int i = 0; i < 2; ++i)
#pragma unroll
        for (int mi = 0; mi < 2; ++mi)
#pragma unroll
            for (int ni = 0; ni < 2; ++ni)
#pragma unroll
                for (int j = 0; j < 4; ++j) {
                    int r = i * 32 + mi * 16 + lhi * 4 + j;
                    int c = wc * 32 + ni * 16 + lr;
                    out[(size_t)NB * NA * ND + (size_t)(brow0 + r) * ND + c] = indiv[i][mi][ni][j];
                }
#undef LOADB
#undef SUBGEMM
#undef WRITEC
#undef STAGE_EDGE
}

extern "C" void kernel_launch(void* const* d_in, const int* in_sizes, int n_in,
                              void* d_out, int out_size, void* d_ws, size_t ws_size,
                              hipStream_t stream)
{
    const float* img  = (const float*)d_in[0];
    const float* edge = (const float*)d_in[1];
    const float* Wagg = (const float*)d_in[2];
    const float* bagg = (const float*)d_in[3];
    const float* Pf   = (const float*)d_in[4];
    const float* Pb   = (const float*)d_in[5];
    const float* sw   = (const float*)d_in[6];
    float* out = (float*)d_out;

    char* ws = (char*)d_ws;
    bf16_t* W1f = (bf16_t*)(ws);                   // 128 KB fragment layout
    bf16_t* W2f = (bf16_t*)(ws + 131072);          // 128 KB
    bf16_t* Pff = (bf16_t*)(ws + 262144);          // 2 MB
    bf16_t* Pbf = (bf16_t*)(ws + 2359296);         // 2 MB

    prep_wfrag<<<64, 256, 0, stream>>>(Wagg, W1f, W2f);
    prep_pfrag2<<<1024, 256, 0, stream>>>(Pf, Pb, Pff, Pbf);
    fused_main<<<NB / BM, 512, 0, stream>>>(img, bagg, edge, W1f, W2f, Pff, Pbf, sw, out);
}